// Round 3
// baseline (513.077 us; speedup 1.0000x reference)
//
#include <hip/hip_runtime.h>

#define NS 10000
#define DD 64
#define HH 128
#define EE 50000
#define SLOPE 0.01f
#define CAP 12

typedef __attribute__((ext_vector_type(8))) short short8;
typedef __attribute__((ext_vector_type(4))) float f32x4;

static __device__ __forceinline__ unsigned short f2bf(float f) {
  unsigned int u = __float_as_uint(f);
  u += 0x7fff + ((u >> 16) & 1);   // round-to-nearest-even
  return (unsigned short)(u >> 16);
}

__device__ __forceinline__ float wave_sum64(float v) {
  #pragma unroll
  for (int m = 32; m >= 1; m >>= 1) v += __shfl_xor(v, m, 64);
  return v;
}

// h = leaky_relu(layer_norm(x)); also emit bf16 copy for MFMA.
__global__ __launch_bounds__(256) void k_ln(const float* __restrict__ x,
    const float* __restrict__ gamma, const float* __restrict__ beta,
    float* __restrict__ h, unsigned short* __restrict__ hbf) {
  int wid = threadIdx.x >> 6;
  int lane = threadIdx.x & 63;
  int row = blockIdx.x * 4 + wid;
  if (row >= NS) return;
  float v = x[row * DD + lane];
  float s = wave_sum64(v);
  float s2 = wave_sum64(v * v);
  float mu = s * (1.0f / 64.0f);
  float var = s2 * (1.0f / 64.0f) - mu * mu;
  float r = rsqrtf(var + 1e-5f);
  float hn = (v - mu) * r * gamma[lane] + beta[lane];
  float hv = hn >= 0.f ? hn : SLOPE * hn;
  h[row * DD + lane] = hv;
  hbf[row * DD + lane] = f2bf(hv);
}

// w2t[(k*64+f)*64 + d] = bf16(w2[k*4096 + d*64 + f])
__global__ __launch_bounds__(256) void k_cast_w2t(const float* __restrict__ w2,
    unsigned short* __restrict__ w2t) {
  int tid = blockIdx.x * 256 + threadIdx.x;
  int c = tid >> 6;
  int d = tid & 63;
  int k = c >> 6, f = c & 63;
  w2t[tid] = f2bf(w2[k * (DD * DD) + d * DD + f]);
}

// u = leaky_relu(ea @ w1 + b1)   [E,64]@[64,128]
__global__ __launch_bounds__(256) void k_u(const float* __restrict__ ea,
    const float* __restrict__ w1, const float* __restrict__ b1,
    float* __restrict__ u) {
  __shared__ float w1s[DD][HH];
  __shared__ float eas[32][DD];
  int t = threadIdx.x;
  #pragma unroll
  for (int i = 0; i < 32; ++i) {
    int idx = t + i * 256;
    w1s[idx >> 7][idx & 127] = w1[idx];
  }
  int row0 = blockIdx.x * 32;
  #pragma unroll
  for (int i = 0; i < 8; ++i) {
    int idx = t + i * 256;
    int r = idx >> 6, d = idx & 63;
    int gr = row0 + r;
    eas[r][d] = (gr < EE) ? ea[gr * DD + d] : 0.f;
  }
  __syncthreads();
  int r = t >> 3;
  int c0 = (t & 7) * 16;
  int gr = row0 + r;
  if (gr >= EE) return;
  float acc[16];
  #pragma unroll
  for (int j = 0; j < 16; ++j) acc[j] = b1[c0 + j];
  for (int d = 0; d < DD; ++d) {
    float a = eas[r][d];
    #pragma unroll
    for (int j = 0; j < 16; ++j) acc[j] += a * w1s[d][c0 + j];
  }
  #pragma unroll
  for (int j = 0; j < 16; ++j) {
    float vv = acc[j];
    u[(size_t)gr * HH + c0 + j] = vv >= 0.f ? vv : SLOPE * vv;
  }
}

// C[n,64] = A[n,64] @ B[64,64]
__global__ __launch_bounds__(256) void k_gemm64(const float* __restrict__ A,
    const float* __restrict__ B, float* __restrict__ C, int n) {
  __shared__ float Bs[DD][DD + 1];
  __shared__ float As[32][DD];
  int t = threadIdx.x;
  #pragma unroll
  for (int i = 0; i < 16; ++i) {
    int idx = t + i * 256;
    Bs[idx >> 6][idx & 63] = B[idx];
  }
  int row0 = blockIdx.x * 32;
  #pragma unroll
  for (int i = 0; i < 8; ++i) {
    int idx = t + i * 256;
    int r = idx >> 6, d = idx & 63;
    int gr = row0 + r;
    As[r][d] = (gr < n) ? A[gr * DD + d] : 0.f;
  }
  __syncthreads();
  int r = t >> 3;
  int c0 = (t & 7) * 8;
  int gr = row0 + r;
  if (gr >= n) return;
  float acc[8] = {};
  for (int d = 0; d < DD; ++d) {
    float a = As[r][d];
    #pragma unroll
    for (int j = 0; j < 8; ++j) acc[j] += a * Bs[d][c0 + j];
  }
  #pragma unroll
  for (int j = 0; j < 8; ++j) C[(size_t)gr * DD + c0 + j] = acc[j];
}

__global__ __launch_bounds__(256) void k_cnt2(const int* __restrict__ ei,
    int* __restrict__ cntsrc, int* __restrict__ cntdst) {
  int e = blockIdx.x * 256 + threadIdx.x;
  if (e < EE) {
    atomicAdd(&cntsrc[ei[e]], 1);
    atomicAdd(&cntdst[ei[EE + e]], 1);
  }
}

// single-block exclusive scan of cntsrc -> rowptr[N+1], also init cursor.
__global__ __launch_bounds__(1024) void k_scan(const int* __restrict__ cntsrc,
    int* __restrict__ rowptr, int* __restrict__ cursor) {
  __shared__ int ps[1024];
  int t = threadIdx.x;
  const int CH = (NS + 1023) / 1024;
  int base = t * CH;
  int sum = 0;
  for (int i = 0; i < CH; ++i) {
    int idx = base + i;
    if (idx < NS) sum += cntsrc[idx];
  }
  ps[t] = sum;
  __syncthreads();
  for (int off = 1; off < 1024; off <<= 1) {
    int v = (t >= off) ? ps[t - off] : 0;
    __syncthreads();
    ps[t] += v;
    __syncthreads();
  }
  int run = ps[t] - sum;
  for (int i = 0; i < CH; ++i) {
    int idx = base + i;
    if (idx < NS) {
      rowptr[idx] = run;
      cursor[idx] = run;
      run += cntsrc[idx];
    }
  }
  if (t == 1023) rowptr[NS] = run;
}

__global__ __launch_bounds__(256) void k_scatter(const int* __restrict__ ei,
    int* __restrict__ cursor, int* __restrict__ eord) {
  int e = blockIdx.x * 256 + threadIdx.x;
  if (e < EE) {
    int s = ei[e];
    int pos = atomicAdd(&cursor[s], 1);
    eord[pos] = e;
  }
}

// Fused T+message: block = 32 src nodes, 8 waves; loop 32 chunks of 256 T-cols
// (4 k x 64 f). MFMA computes T-chunk -> LDS; each wave applies it to the
// edges of its 4 nodes, accumulating msg in registers; atomic flush per pass.
__global__ __launch_bounds__(512) void k_fused(
    const unsigned short* __restrict__ hbf, const unsigned short* __restrict__ w2t,
    const float* __restrict__ u, const float* __restrict__ cc,
    const int* __restrict__ rowptr, const int* __restrict__ eord,
    const int* __restrict__ ei, float* __restrict__ agg) {
  __shared__ unsigned short hs[32][72];
  __shared__ float Ts[4][32][65];
  __shared__ int pmax_s;
  int t = threadIdx.x;
  int s0 = blockIdx.x * 32;
  if (t == 0) pmax_s = 0;
  if (t < 256) {
    int r = t >> 3, c = (t & 7) * 8;
    int n = s0 + r;
    short8 v = {};
    if (n < NS) v = *(const short8*)(hbf + (size_t)n * DD + c);
    *(short8*)(&hs[r][c]) = v;
  }
  int w = t >> 6, lane = t & 63;
  int lg = lane >> 4, lr = lane & 15;
  int deg[4], beg[4];
  float cs[4];
  int pw = 0;
  #pragma unroll
  for (int ln = 0; ln < 4; ++ln) {
    int n = s0 + w * 4 + ln;
    int b = 0, d = 0;
    float cv = 0.f;
    if (n < NS) {
      b = rowptr[n];
      d = rowptr[n + 1] - b;
      cv = cc[(size_t)n * DD + lane];
    }
    beg[ln] = b; deg[ln] = d; cs[ln] = cv;
    int pn = (d + CAP - 1) / CAP;
    pw = pn > pw ? pn : pw;
  }
  if (lane == 0) atomicMax(&pmax_s, pw);
  __syncthreads();
  int P = pmax_s;
  if (P == 0) return;

  // A-fragments (persistent): rows = nodes, k = ks*32 + lg*8
  short8 a00 = *(const short8*)(&hs[lr][lg * 8]);
  short8 a01 = *(const short8*)(&hs[lr][32 + lg * 8]);
  short8 a10 = *(const short8*)(&hs[16 + lr][lg * 8]);
  short8 a11 = *(const short8*)(&hs[16 + lr][32 + lg * 8]);

  for (int p = 0; p < P; ++p) {
    int eoff[4][CAP];
    float acc[4][CAP];
    #pragma unroll
    for (int ln = 0; ln < 4; ++ln) {
      #pragma unroll
      for (int j = 0; j < CAP; ++j) {
        int eo = 0;
        if (p * CAP + j < deg[ln]) {
          int e = eord[beg[ln] + p * CAP + j];
          eo = __builtin_amdgcn_readfirstlane(e);
        }
        eoff[ln][j] = eo;
        acc[ln][j] = cs[ln];
      }
    }
    for (int ch = 0; ch < 32; ++ch) {
      __syncthreads();   // prev chunk's Ts reads done before overwrite
      #pragma unroll
      for (int nj = 0; nj < 2; ++nj) {
        int gc = ch * 256 + (w * 2 + nj) * 16 + lr;
        const unsigned short* bp = w2t + (size_t)gc * DD;
        short8 b0 = *(const short8*)(bp + lg * 8);
        short8 b1 = *(const short8*)(bp + 32 + lg * 8);
        f32x4 c0 = {}, c1 = {};
        c0 = __builtin_amdgcn_mfma_f32_16x16x32_bf16(a00, b0, c0, 0, 0, 0);
        c0 = __builtin_amdgcn_mfma_f32_16x16x32_bf16(a01, b1, c0, 0, 0, 0);
        c1 = __builtin_amdgcn_mfma_f32_16x16x32_bf16(a10, b0, c1, 0, 0, 0);
        c1 = __builtin_amdgcn_mfma_f32_16x16x32_bf16(a11, b1, c1, 0, 0, 0);
        int cl = (w * 2 + nj) * 16 + lr;
        int kk = cl >> 6, f = cl & 63;
        #pragma unroll
        for (int r = 0; r < 4; ++r) {
          Ts[kk][lg * 4 + r][f] = c0[r];
          Ts[kk][16 + lg * 4 + r][f] = c1[r];
        }
      }
      __syncthreads();
      #pragma unroll
      for (int ln = 0; ln < 4; ++ln) {
        int nl = w * 4 + ln;
        float t0 = Ts[0][nl][lane], t1 = Ts[1][nl][lane];
        float t2 = Ts[2][nl][lane], t3 = Ts[3][nl][lane];
        #pragma unroll
        for (int j = 0; j < CAP; ++j) {
          if (p * CAP + j < deg[ln]) {
            const float4* up =
                (const float4*)(u + (size_t)eoff[ln][j] * HH + ch * 4);
            float4 uv = *up;
            float a = acc[ln][j];
            a = fmaf(uv.x, t0, a);
            a = fmaf(uv.y, t1, a);
            a = fmaf(uv.z, t2, a);
            a = fmaf(uv.w, t3, a);
            acc[ln][j] = a;
          }
        }
      }
    }
    #pragma unroll
    for (int ln = 0; ln < 4; ++ln) {
      #pragma unroll
      for (int j = 0; j < CAP; ++j) {
        if (p * CAP + j < deg[ln]) {
          int dst = ei[EE + eoff[ln][j]];
          atomicAdd(&agg[(size_t)dst * DD + lane], acc[ln][j]);
        }
      }
    }
  }
}

// out = x + agg/max(cnt,1) + h@root + bias
__global__ __launch_bounds__(256) void k_final(const float* __restrict__ x,
    const float* __restrict__ h, const float* __restrict__ root,
    const float* __restrict__ bias, const float* __restrict__ agg,
    const int* __restrict__ cnt, float* __restrict__ out) {
  __shared__ float Bs[DD][DD + 1];
  __shared__ float As[32][DD];
  int t = threadIdx.x;
  #pragma unroll
  for (int i = 0; i < 16; ++i) {
    int idx = t + i * 256;
    Bs[idx >> 6][idx & 63] = root[idx];
  }
  int row0 = blockIdx.x * 32;
  #pragma unroll
  for (int i = 0; i < 8; ++i) {
    int idx = t + i * 256;
    int r = idx >> 6, d = idx & 63;
    int gr = row0 + r;
    As[r][d] = (gr < NS) ? h[gr * DD + d] : 0.f;
  }
  __syncthreads();
  int r = t >> 3;
  int c0 = (t & 7) * 8;
  int gr = row0 + r;
  if (gr >= NS) return;
  float acc[8] = {};
  for (int d = 0; d < DD; ++d) {
    float a = As[r][d];
    #pragma unroll
    for (int j = 0; j < 8; ++j) acc[j] += a * Bs[d][c0 + j];
  }
  float inv = 1.0f / fmaxf((float)cnt[gr], 1.0f);
  #pragma unroll
  for (int j = 0; j < 8; ++j) {
    size_t gi = (size_t)gr * DD + c0 + j;
    out[gi] = x[gi] + agg[gi] * inv + acc[j] + bias[c0 + j];
  }
}

extern "C" void kernel_launch(void* const* d_in, const int* in_sizes, int n_in,
                              void* d_out, int out_size, void* d_ws, size_t ws_size,
                              hipStream_t stream) {
  const float* x     = (const float*)d_in[0];
  const float* ea    = (const float*)d_in[1];
  const float* gamma = (const float*)d_in[2];
  const float* beta  = (const float*)d_in[3];
  const float* w1    = (const float*)d_in[4];
  const float* b1    = (const float*)d_in[5];
  const float* w2    = (const float*)d_in[6];
  const float* b2    = (const float*)d_in[7];
  const float* root  = (const float*)d_in[8];
  const float* bias  = (const float*)d_in[9];
  const int*   ei    = (const int*)d_in[10];
  float* out = (float*)d_out;

  char* p = (char*)d_ws;
  auto carve = [&](size_t bytes) {
    char* q = p;
    p += (bytes + 255) & ~(size_t)255;
    return q;
  };
  float* h            = (float*)carve(sizeof(float) * NS * DD);
  unsigned short* hbf = (unsigned short*)carve(sizeof(short) * NS * DD);
  float* cc           = (float*)carve(sizeof(float) * NS * DD);
  float* agg          = (float*)carve(sizeof(float) * NS * DD);
  int* cntdst         = (int*)carve(sizeof(int) * NS);
  int* cntsrc         = (int*)carve(sizeof(int) * NS);
  int* rowptr         = (int*)carve(sizeof(int) * (NS + 1));
  int* cursor         = (int*)carve(sizeof(int) * NS);
  int* eord           = (int*)carve(sizeof(int) * EE);
  unsigned short* w2t = (unsigned short*)carve(sizeof(short) * HH * DD * DD);
  float* u            = (float*)carve(sizeof(float) * (size_t)EE * HH);

  hipMemsetAsync(agg, 0, sizeof(float) * NS * DD, stream);
  hipMemsetAsync(cntdst, 0, sizeof(int) * NS, stream);
  hipMemsetAsync(cntsrc, 0, sizeof(int) * NS, stream);

  k_ln<<<dim3((NS + 3) / 4), dim3(256), 0, stream>>>(x, gamma, beta, h, hbf);
  k_cast_w2t<<<dim3(HH * DD * DD / 256), dim3(256), 0, stream>>>(w2, w2t);
  k_u<<<dim3((EE + 31) / 32), dim3(256), 0, stream>>>(ea, w1, b1, u);
  k_gemm64<<<dim3((NS + 31) / 32), dim3(256), 0, stream>>>(h, b2, cc, NS);
  k_cnt2<<<dim3((EE + 255) / 256), dim3(256), 0, stream>>>(ei, cntsrc, cntdst);
  k_scan<<<dim3(1), dim3(1024), 0, stream>>>(cntsrc, rowptr, cursor);
  k_scatter<<<dim3((EE + 255) / 256), dim3(256), 0, stream>>>(ei, cursor, eord);

  k_fused<<<dim3((NS + 31) / 32), dim3(512), 0, stream>>>(hbf, w2t, u, cc,
                                                          rowptr, eord, ei, agg);

  k_final<<<dim3((NS + 31) / 32), dim3(256), 0, stream>>>(x, h, root, bias, agg,
                                                          cntdst, out);
}

// Round 4
// 185.409 us; speedup vs baseline: 2.7673x; 2.7673x over previous
//
#include <hip/hip_runtime.h>

#define NS 10000
#define DD 64
#define HH 128
#define EE 50000
#define SLOPE 0.01f

typedef __attribute__((ext_vector_type(8))) short short8;
typedef __attribute__((ext_vector_type(4))) float f32x4;

static __device__ __forceinline__ unsigned short f2bf(float f) {
  unsigned int u = __float_as_uint(f);
  u += 0x7fff + ((u >> 16) & 1);   // round-to-nearest-even
  return (unsigned short)(u >> 16);
}

__device__ __forceinline__ float wave_sum64(float v) {
  #pragma unroll
  for (int m = 32; m >= 1; m >>= 1) v += __shfl_xor(v, m, 64);
  return v;
}

// h = leaky_relu(layer_norm(x)); also emit bf16 copy for MFMA.
__global__ __launch_bounds__(256) void k_ln(const float* __restrict__ x,
    const float* __restrict__ gamma, const float* __restrict__ beta,
    float* __restrict__ h, unsigned short* __restrict__ hbf) {
  int wid = threadIdx.x >> 6;
  int lane = threadIdx.x & 63;
  int row = blockIdx.x * 4 + wid;
  if (row >= NS) return;
  float v = x[row * DD + lane];
  float s = wave_sum64(v);
  float s2 = wave_sum64(v * v);
  float mu = s * (1.0f / 64.0f);
  float var = s2 * (1.0f / 64.0f) - mu * mu;
  float r = rsqrtf(var + 1e-5f);
  float hn = (v - mu) * r * gamma[lane] + beta[lane];
  float hv = hn >= 0.f ? hn : SLOPE * hn;
  h[row * DD + lane] = hv;
  hbf[row * DD + lane] = f2bf(hv);
}

// w2t2[(f*128+k)*64 + d] = bf16(w2[k*4096 + d*64 + f])  (c2 = f*128+k order)
__global__ __launch_bounds__(256) void k_cast_w2t2(const float* __restrict__ w2,
    unsigned short* __restrict__ w2t2) {
  int tid = blockIdx.x * 256 + threadIdx.x;   // 524288
  int d = tid & 63;
  int c2 = tid >> 6;
  int f = c2 >> 7, k = c2 & 127;
  w2t2[tid] = f2bf(w2[k * (DD * DD) + d * DD + f]);
}

// ubf = bf16(leaky_relu(ea @ w1 + b1))   [E,64]@[64,128]
__global__ __launch_bounds__(256) void k_u(const float* __restrict__ ea,
    const float* __restrict__ w1, const float* __restrict__ b1,
    unsigned short* __restrict__ ubf) {
  __shared__ float w1s[DD][HH];
  __shared__ float eas[32][DD];
  int t = threadIdx.x;
  #pragma unroll
  for (int i = 0; i < 32; ++i) {
    int idx = t + i * 256;
    w1s[idx >> 7][idx & 127] = w1[idx];
  }
  int row0 = blockIdx.x * 32;
  #pragma unroll
  for (int i = 0; i < 8; ++i) {
    int idx = t + i * 256;
    int r = idx >> 6, d = idx & 63;
    int gr = row0 + r;
    eas[r][d] = (gr < EE) ? ea[gr * DD + d] : 0.f;
  }
  __syncthreads();
  int r = t >> 3;
  int c0 = (t & 7) * 16;
  int gr = row0 + r;
  if (gr >= EE) return;
  float acc[16];
  #pragma unroll
  for (int j = 0; j < 16; ++j) acc[j] = b1[c0 + j];
  for (int d = 0; d < DD; ++d) {
    float a = eas[r][d];
    #pragma unroll
    for (int j = 0; j < 16; ++j) acc[j] += a * w1s[d][c0 + j];
  }
  #pragma unroll
  for (int j = 0; j < 16; ++j) {
    float vv = acc[j];
    ubf[(size_t)gr * HH + c0 + j] = f2bf(vv >= 0.f ? vv : SLOPE * vv);
  }
}

// C[n,64] = A[n,64] @ B[64,64]
__global__ __launch_bounds__(256) void k_gemm64(const float* __restrict__ A,
    const float* __restrict__ B, float* __restrict__ C, int n) {
  __shared__ float Bs[DD][DD + 1];
  __shared__ float As[32][DD];
  int t = threadIdx.x;
  #pragma unroll
  for (int i = 0; i < 16; ++i) {
    int idx = t + i * 256;
    Bs[idx >> 6][idx & 63] = B[idx];
  }
  int row0 = blockIdx.x * 32;
  #pragma unroll
  for (int i = 0; i < 8; ++i) {
    int idx = t + i * 256;
    int r = idx >> 6, d = idx & 63;
    int gr = row0 + r;
    As[r][d] = (gr < n) ? A[gr * DD + d] : 0.f;
  }
  __syncthreads();
  int r = t >> 3;
  int c0 = (t & 7) * 8;
  int gr = row0 + r;
  if (gr >= n) return;
  float acc[8] = {};
  for (int d = 0; d < DD; ++d) {
    float a = As[r][d];
    #pragma unroll
    for (int j = 0; j < 8; ++j) acc[j] += a * Bs[d][c0 + j];
  }
  #pragma unroll
  for (int j = 0; j < 8; ++j) C[(size_t)gr * DD + c0 + j] = acc[j];
}

__global__ __launch_bounds__(256) void k_cnt2(const int* __restrict__ ei,
    int* __restrict__ cntsrc, int* __restrict__ cntdst) {
  int e = blockIdx.x * 256 + threadIdx.x;
  if (e < EE) {
    atomicAdd(&cntsrc[ei[e]], 1);
    atomicAdd(&cntdst[ei[EE + e]], 1);
  }
}

// single-block exclusive scan of cntsrc -> rowptr[N+1], also init cursor.
__global__ __launch_bounds__(1024) void k_scan(const int* __restrict__ cntsrc,
    int* __restrict__ rowptr, int* __restrict__ cursor) {
  __shared__ int ps[1024];
  int t = threadIdx.x;
  const int CH = (NS + 1023) / 1024;
  int base = t * CH;
  int sum = 0;
  for (int i = 0; i < CH; ++i) {
    int idx = base + i;
    if (idx < NS) sum += cntsrc[idx];
  }
  ps[t] = sum;
  __syncthreads();
  for (int off = 1; off < 1024; off <<= 1) {
    int v = (t >= off) ? ps[t - off] : 0;
    __syncthreads();
    ps[t] += v;
    __syncthreads();
  }
  int run = ps[t] - sum;
  for (int i = 0; i < CH; ++i) {
    int idx = base + i;
    if (idx < NS) {
      rowptr[idx] = run;
      cursor[idx] = run;
      run += cntsrc[idx];
    }
  }
  if (t == 1023) rowptr[NS] = run;
}

__global__ __launch_bounds__(256) void k_scatter(const int* __restrict__ ei,
    int* __restrict__ cursor, int* __restrict__ eord) {
  int e = blockIdx.x * 256 + threadIdx.x;
  if (e < EE) {
    int s = ei[e];
    int pos = atomicAdd(&cursor[s], 1);
    eord[pos] = e;
  }
}

// Tt[(n-n0)*8192 + c2] (bf16) = sum_d hbf[n,d] * w2t2[c2,d], c2 = f*128+k.
// Tile 64 rows x 256 cols, 4 waves.
__global__ __launch_bounds__(256) void k_T_mfma(
    const unsigned short* __restrict__ hbf, const unsigned short* __restrict__ w2t2,
    unsigned short* __restrict__ T, int n0, int n1) {
  __shared__ unsigned short As[64][72];
  __shared__ unsigned short Bs[256][72];
  int t = threadIdx.x;
  int row0 = n0 + blockIdx.x * 64;
  int col0 = blockIdx.y * 256;
  #pragma unroll
  for (int i = 0; i < 2; ++i) {
    int idx = t + i * 256;
    int r = idx >> 3, cc = (idx & 7) * 8;
    int gr = row0 + r;
    short8 v = {};
    if (gr < n1) v = *(const short8*)(hbf + (size_t)gr * DD + cc);
    *(short8*)(&As[r][cc]) = v;
  }
  #pragma unroll
  for (int i = 0; i < 8; ++i) {
    int idx = t + i * 256;
    int cL = idx >> 3, rr = (idx & 7) * 8;
    int gc = col0 + cL;
    short8 v = *(const short8*)(w2t2 + (size_t)gc * DD + rr);
    *(short8*)(&Bs[cL][rr]) = v;
  }
  __syncthreads();
  int w = t >> 6, lane = t & 63;
  int lr = lane & 15, lg = lane >> 4;
  f32x4 acc[4][4] = {};
  #pragma unroll
  for (int kk = 0; kk < 64; kk += 32) {
    short8 a[4], b[4];
    #pragma unroll
    for (int mi = 0; mi < 4; ++mi)
      a[mi] = *(const short8*)(&As[mi * 16 + lr][kk + lg * 8]);
    #pragma unroll
    for (int ni = 0; ni < 4; ++ni)
      b[ni] = *(const short8*)(&Bs[w * 64 + ni * 16 + lr][kk + lg * 8]);
    #pragma unroll
    for (int mi = 0; mi < 4; ++mi)
      #pragma unroll
      for (int ni = 0; ni < 4; ++ni)
        acc[mi][ni] = __builtin_amdgcn_mfma_f32_16x16x32_bf16(
            a[mi], b[ni], acc[mi][ni], 0, 0, 0);
  }
  #pragma unroll
  for (int mi = 0; mi < 4; ++mi) {
    int gr0 = row0 + mi * 16 + lg * 4;
    #pragma unroll
    for (int ni = 0; ni < 4; ++ni) {
      int gc = col0 + w * 64 + ni * 16 + lr;
      #pragma unroll
      for (int reg = 0; reg < 4; ++reg) {
        int gr = gr0 + reg;
        if (gr < n1)
          T[(size_t)(gr - n0) * (HH * DD) + gc] = f2bf(acc[mi][ni][reg]);
      }
    }
  }
}

// Wave-per-node message pass: B-frags = Tt[s] (16KB, read once), A-frags =
// gathered bf16 u-rows of <=16 edges; 16 MFMA -> msg tile; +cc; atomic flush.
__global__ __launch_bounds__(256) void k_msg_wave(
    const unsigned short* __restrict__ ubf, const unsigned short* __restrict__ T,
    const float* __restrict__ cc, const int* __restrict__ ei,
    const int* __restrict__ rowptr, const int* __restrict__ eord,
    float* __restrict__ agg, int n0, int n1) {
  int wid = threadIdx.x >> 6;
  int lane = threadIdx.x & 63;
  int s = n0 + blockIdx.x * 4 + wid;
  if (s >= n1) return;
  int beg = rowptr[s];
  int deg = rowptr[s + 1] - beg;
  if (deg == 0) return;
  int lr = lane & 15, lg = lane >> 4;
  const unsigned short* tp = T + (size_t)(s - n0) * (HH * DD);
  short8 b[4][4];   // [ftile][kstep]
  #pragma unroll
  for (int ft = 0; ft < 4; ++ft)
    #pragma unroll
    for (int kk = 0; kk < 4; ++kk)
      b[ft][kk] =
          *(const short8*)(tp + (ft * 16 + lr) * HH + kk * 32 + lg * 8);
  float clv[4];
  #pragma unroll
  for (int ft = 0; ft < 4; ++ft) clv[ft] = cc[(size_t)s * DD + ft * 16 + lr];

  for (int p0 = 0; p0 < deg; p0 += 16) {
    int ev = 0, dv = 0;
    if (lane < 16 && p0 + lane < deg) {
      ev = eord[beg + p0 + lane];
      dv = ei[EE + ev];
    }
    int e_lr = __shfl(ev, (p0 + lr < deg) ? lr : 0);
    const unsigned short* up = ubf + (size_t)e_lr * HH;
    short8 a[4];
    #pragma unroll
    for (int kk = 0; kk < 4; ++kk)
      a[kk] = *(const short8*)(up + kk * 32 + lg * 8);
    f32x4 acc[4] = {};
    #pragma unroll
    for (int kk = 0; kk < 4; ++kk)
      #pragma unroll
      for (int ft = 0; ft < 4; ++ft)
        acc[ft] = __builtin_amdgcn_mfma_f32_16x16x32_bf16(a[kk], b[ft][kk],
                                                          acc[ft], 0, 0, 0);
    #pragma unroll
    for (int r = 0; r < 4; ++r) {
      int idx = p0 + lg * 4 + r;
      int dstn = __shfl(dv, lg * 4 + r);
      if (idx < deg) {
        #pragma unroll
        for (int ft = 0; ft < 4; ++ft)
          atomicAdd(&agg[(size_t)dstn * DD + ft * 16 + lr],
                    acc[ft][r] + clv[ft]);
      }
    }
  }
}

// out = x + agg/max(cnt,1) + h@root + bias
__global__ __launch_bounds__(256) void k_final(const float* __restrict__ x,
    const float* __restrict__ h, const float* __restrict__ root,
    const float* __restrict__ bias, const float* __restrict__ agg,
    const int* __restrict__ cnt, float* __restrict__ out) {
  __shared__ float Bs[DD][DD + 1];
  __shared__ float As[32][DD];
  int t = threadIdx.x;
  #pragma unroll
  for (int i = 0; i < 16; ++i) {
    int idx = t + i * 256;
    Bs[idx >> 6][idx & 63] = root[idx];
  }
  int row0 = blockIdx.x * 32;
  #pragma unroll
  for (int i = 0; i < 8; ++i) {
    int idx = t + i * 256;
    int r = idx >> 6, d = idx & 63;
    int gr = row0 + r;
    As[r][d] = (gr < NS) ? h[gr * DD + d] : 0.f;
  }
  __syncthreads();
  int r = t >> 3;
  int c0 = (t & 7) * 8;
  int gr = row0 + r;
  if (gr >= NS) return;
  float acc[8] = {};
  for (int d = 0; d < DD; ++d) {
    float a = As[r][d];
    #pragma unroll
    for (int j = 0; j < 8; ++j) acc[j] += a * Bs[d][c0 + j];
  }
  float inv = 1.0f / fmaxf((float)cnt[gr], 1.0f);
  #pragma unroll
  for (int j = 0; j < 8; ++j) {
    size_t gi = (size_t)gr * DD + c0 + j;
    out[gi] = x[gi] + agg[gi] * inv + acc[j] + bias[c0 + j];
  }
}

extern "C" void kernel_launch(void* const* d_in, const int* in_sizes, int n_in,
                              void* d_out, int out_size, void* d_ws, size_t ws_size,
                              hipStream_t stream) {
  const float* x     = (const float*)d_in[0];
  const float* ea    = (const float*)d_in[1];
  const float* gamma = (const float*)d_in[2];
  const float* beta  = (const float*)d_in[3];
  const float* w1    = (const float*)d_in[4];
  const float* b1    = (const float*)d_in[5];
  const float* w2    = (const float*)d_in[6];
  const float* b2    = (const float*)d_in[7];
  const float* root  = (const float*)d_in[8];
  const float* bias  = (const float*)d_in[9];
  const int*   ei    = (const int*)d_in[10];
  float* out = (float*)d_out;

  char* p = (char*)d_ws;
  auto carve = [&](size_t bytes) {
    char* q = p;
    p += (bytes + 255) & ~(size_t)255;
    return q;
  };
  float* h            = (float*)carve(sizeof(float) * NS * DD);
  unsigned short* hbf = (unsigned short*)carve(sizeof(short) * NS * DD);
  float* cc           = (float*)carve(sizeof(float) * NS * DD);
  float* agg          = (float*)carve(sizeof(float) * NS * DD);
  int* cntdst         = (int*)carve(sizeof(int) * NS);
  int* cntsrc         = (int*)carve(sizeof(int) * NS);
  int* rowptr         = (int*)carve(sizeof(int) * (NS + 1));
  int* cursor         = (int*)carve(sizeof(int) * NS);
  int* eord           = (int*)carve(sizeof(int) * EE);
  unsigned short* w2t2 = (unsigned short*)carve(sizeof(short) * HH * DD * DD);
  unsigned short* ubf = (unsigned short*)carve(sizeof(short) * (size_t)EE * HH);
  size_t fixed = (size_t)(p - (char*)d_ws);

  // Node-chunked Tt buffer: rows of 8192 bf16 (16KB each).
  size_t freeb = (ws_size > fixed) ? (ws_size - fixed - 256) : 0;
  int rows = (int)(freeb / (sizeof(short) * HH * DD));
  if (rows > NS) rows = NS;
  if (rows < 64) rows = 64;   // minimum one tile (round-2 evidence: ws is large)
  rows &= ~63;                // multiple of 64 tiles
  unsigned short* Tt = (unsigned short*)carve(sizeof(short) * (size_t)rows * HH * DD);

  hipMemsetAsync(agg, 0, sizeof(float) * NS * DD, stream);
  hipMemsetAsync(cntdst, 0, sizeof(int) * NS, stream);
  hipMemsetAsync(cntsrc, 0, sizeof(int) * NS, stream);

  k_ln<<<dim3((NS + 3) / 4), dim3(256), 0, stream>>>(x, gamma, beta, h, hbf);
  k_cast_w2t2<<<dim3(HH * DD * DD / 256), dim3(256), 0, stream>>>(w2, w2t2);
  k_u<<<dim3((EE + 31) / 32), dim3(256), 0, stream>>>(ea, w1, b1, ubf);
  k_gemm64<<<dim3((NS + 31) / 32), dim3(256), 0, stream>>>(h, b2, cc, NS);
  k_cnt2<<<dim3((EE + 255) / 256), dim3(256), 0, stream>>>(ei, cntsrc, cntdst);
  k_scan<<<dim3(1), dim3(1024), 0, stream>>>(cntsrc, rowptr, cursor);
  k_scatter<<<dim3((EE + 255) / 256), dim3(256), 0, stream>>>(ei, cursor, eord);

  for (int n0 = 0; n0 < NS; n0 += rows) {
    int n1 = n0 + rows;
    if (n1 > NS) n1 = NS;
    int nr = n1 - n0;
    k_T_mfma<<<dim3((nr + 63) / 64, (HH * DD) / 256), dim3(256), 0, stream>>>(
        hbf, w2t2, Tt, n0, n1);
    k_msg_wave<<<dim3((nr + 3) / 4), dim3(256), 0, stream>>>(
        ubf, Tt, cc, ei, rowptr, eord, agg, n0, n1);
  }

  k_final<<<dim3((NS + 31) / 32), dim3(256), 0, stream>>>(x, h, root, bias, agg,
                                                          cntdst, out);
}